// Round 1
// baseline (1169.972 us; speedup 1.0000x reference)
//
#include <hip/hip_runtime.h>
#include <hip/hip_bf16.h>

#define NN 100000
#define NE 1600000
#define FF 64
#define HH 128
#define OO 10
#define NL 3
#define LNEPS 1e-5f

// ---------------- CSR build ----------------
__global__ void k_deg(const int* __restrict__ dst, int* __restrict__ deg){
  int e = blockIdx.x*256 + threadIdx.x;
  if(e<NE) atomicAdd(&deg[dst[e]], 1);
}

__global__ void k_invdeg(const int* __restrict__ deg, float* __restrict__ invd){
  int i = blockIdx.x*256 + threadIdx.x;
  if(i<NN) invd[i] = 1.0f / fmaxf((float)deg[i], 1.0f);
}

__global__ void k_scan1(const int* __restrict__ deg, int* __restrict__ exc, int* __restrict__ bsum){
  __shared__ int s[512];
  int i = blockIdx.x*512 + threadIdx.x;
  int v = (i<NN)? deg[i] : 0;
  s[threadIdx.x] = v;
  __syncthreads();
  for(int off=1; off<512; off<<=1){
    int t = (threadIdx.x>= (unsigned)off)? s[threadIdx.x-off] : 0;
    __syncthreads();
    s[threadIdx.x] += t;
    __syncthreads();
  }
  if(i<NN) exc[i] = s[threadIdx.x] - v;
  if(threadIdx.x==511) bsum[blockIdx.x] = s[511];
}

__global__ void k_scan2(const int* __restrict__ bsum, int* __restrict__ bexc, int nb){
  __shared__ int s[256];
  int t = threadIdx.x;
  int v = (t<nb)? bsum[t] : 0;
  s[t]=v; __syncthreads();
  for(int off=1; off<256; off<<=1){
    int x = (t>=off)? s[t-off]:0;
    __syncthreads();
    s[t]+=x;
    __syncthreads();
  }
  if(t<nb) bexc[t] = s[t]-v;
}

__global__ void k_scan3(int* __restrict__ rowoff, const int* __restrict__ bexc){
  int i = blockIdx.x*512+threadIdx.x;
  if(i<NN) rowoff[i] += bexc[blockIdx.x];
  if(i==0) rowoff[NN] = NE;
}

__global__ void k_scatter(const int* __restrict__ src, const int* __restrict__ dst,
                          const int* __restrict__ rowoff, int* __restrict__ cursor,
                          int* __restrict__ csr){
  int e = blockIdx.x*256+threadIdx.x;
  if(e<NE){
    int d = dst[e];
    int p = atomicAdd(&cursor[d],1);
    csr[rowoff[d]+p] = src[e];
  }
}

// ---------------- mean aggregation: one wave per node ----------------
__global__ __launch_bounds__(256) void k_agg(const float* __restrict__ h, const int* __restrict__ csr,
                                             const int* __restrict__ rowoff, const float* __restrict__ invd,
                                             float* __restrict__ agg){
  int wave = threadIdx.x>>6;
  int lane = threadIdx.x&63;
  int n = blockIdx.x*4 + wave;
  if(n>=NN) return;
  int beg=rowoff[n], end=rowoff[n+1];
  float ax=0.f, ay=0.f;
  const float2* hp=(const float2*)h;
  for(int j=beg;j<end;j++){
    int sN=csr[j];
    float2 v = hp[(size_t)sN*64 + lane];
    ax+=v.x; ay+=v.y;
  }
  float sc = invd[n];
  ((float2*)agg)[(size_t)n*64+lane] = make_float2(ax*sc, ay*sc);
}

// ---------------- generic MLP GEMM: C = act(A[N,K] @ W[K,128] + b) ----------------
template<int K, int ACT>
__global__ __launch_bounds__(256) void k_gemm(const float* __restrict__ A, const float* __restrict__ W,
                                              const float* __restrict__ bias, float* __restrict__ C){
  __shared__ float As[32][68];
  __shared__ float Ws[32][128];
  int tid=threadIdx.x;
  int tc=tid&31, tr=tid>>5;
  int node0=blockIdx.x*64;
  float acc[8][4]={};
  for(int kc=0;kc<K;kc+=32){
    __syncthreads();
    #pragma unroll
    for(int q=0;q<2;q++){
      int idx=tid+256*q;
      int nl=idx>>3, kq=idx&7;
      int node=node0+nl;
      float4 v = make_float4(0.f,0.f,0.f,0.f);
      if(node<NN) v = *(const float4*)&A[(size_t)node*K + kc + kq*4];
      As[kq*4+0][nl]=v.x; As[kq*4+1][nl]=v.y; As[kq*4+2][nl]=v.z; As[kq*4+3][nl]=v.w;
    }
    #pragma unroll
    for(int q=0;q<4;q++){
      int idx=tid+256*q;
      int kl=idx>>5, cq=idx&31;
      *(float4*)&Ws[kl][cq*4] = *(const float4*)&W[(size_t)(kc+kl)*HH + cq*4];
    }
    __syncthreads();
    #pragma unroll
    for(int k=0;k<32;k++){
      float4 w=*(float4*)&Ws[k][tc*4];
      float4 a0=*(float4*)&As[k][tr*8];
      float4 a1=*(float4*)&As[k][tr*8+4];
      float av[8]={a0.x,a0.y,a0.z,a0.w,a1.x,a1.y,a1.z,a1.w};
      float wv[4]={w.x,w.y,w.z,w.w};
      #pragma unroll
      for(int j=0;j<8;j++)
        #pragma unroll
        for(int c=0;c<4;c++) acc[j][c] = fmaf(av[j], wv[c], acc[j][c]);
    }
  }
  float4 bb=*(const float4*)&bias[tc*4];
  float bv[4]={bb.x,bb.y,bb.z,bb.w};
  #pragma unroll
  for(int j=0;j<8;j++){
    int node=node0+tr*8+j;
    if(node<NN){
      float ov[4];
      #pragma unroll
      for(int c=0;c<4;c++){ float x=acc[j][c]+bv[c]; if(ACT) x=fmaxf(x,0.f); ov[c]=x; }
      float4 o; o.x=ov[0]; o.y=ov[1]; o.z=ov[2]; o.w=ov[3];
      *(float4*)&C[(size_t)node*HH + tc*4]=o;
    }
  }
}

// ---------------- fused SAGE layer: h = LN(relu(h@Ws + agg@Wn + b)) ----------------
__global__ __launch_bounds__(256) void k_sage(const float* __restrict__ h, const float* __restrict__ ag,
                                              const float* __restrict__ Wself, const float* __restrict__ Wneigh,
                                              const float* __restrict__ bias, const float* __restrict__ lng,
                                              const float* __restrict__ lnb, float* __restrict__ hout){
  __shared__ float Ah[32][68], Ag[32][68];
  __shared__ float Ws[32][128], Wn[32][128];
  int tid=threadIdx.x, tc=tid&31, tr=tid>>5;
  int node0=blockIdx.x*64;
  float acc[8][4]={};
  for(int kc=0;kc<HH;kc+=32){
    __syncthreads();
    #pragma unroll
    for(int q=0;q<2;q++){
      int idx=tid+256*q;
      int nl=idx>>3, kq=idx&7;
      int node=node0+nl;
      float4 v=make_float4(0.f,0.f,0.f,0.f), u=make_float4(0.f,0.f,0.f,0.f);
      if(node<NN){
        v=*(const float4*)&h[(size_t)node*HH+kc+kq*4];
        u=*(const float4*)&ag[(size_t)node*HH+kc+kq*4];
      }
      Ah[kq*4+0][nl]=v.x; Ah[kq*4+1][nl]=v.y; Ah[kq*4+2][nl]=v.z; Ah[kq*4+3][nl]=v.w;
      Ag[kq*4+0][nl]=u.x; Ag[kq*4+1][nl]=u.y; Ag[kq*4+2][nl]=u.z; Ag[kq*4+3][nl]=u.w;
    }
    #pragma unroll
    for(int q=0;q<4;q++){
      int idx=tid+256*q;
      int kl=idx>>5, cq=idx&31;
      *(float4*)&Ws[kl][cq*4]=*(const float4*)&Wself[(size_t)(kc+kl)*HH+cq*4];
      *(float4*)&Wn[kl][cq*4]=*(const float4*)&Wneigh[(size_t)(kc+kl)*HH+cq*4];
    }
    __syncthreads();
    #pragma unroll
    for(int k=0;k<32;k++){
      float4 w1=*(float4*)&Ws[k][tc*4];
      float4 w2=*(float4*)&Wn[k][tc*4];
      float4 a0=*(float4*)&Ah[k][tr*8];
      float4 a1=*(float4*)&Ah[k][tr*8+4];
      float4 g0=*(float4*)&Ag[k][tr*8];
      float4 g1=*(float4*)&Ag[k][tr*8+4];
      float av[8]={a0.x,a0.y,a0.z,a0.w,a1.x,a1.y,a1.z,a1.w};
      float gv[8]={g0.x,g0.y,g0.z,g0.w,g1.x,g1.y,g1.z,g1.w};
      float w1v[4]={w1.x,w1.y,w1.z,w1.w};
      float w2v[4]={w2.x,w2.y,w2.z,w2.w};
      #pragma unroll
      for(int j=0;j<8;j++)
        #pragma unroll
        for(int c=0;c<4;c++)
          acc[j][c] = fmaf(gv[j], w2v[c], fmaf(av[j], w1v[c], acc[j][c]));
    }
  }
  float4 bb=*(const float4*)&bias[tc*4];
  float4 gsc=*(const float4*)&lng[tc*4];
  float4 gof=*(const float4*)&lnb[tc*4];
  float bv[4]={bb.x,bb.y,bb.z,bb.w};
  float sv[4]={gsc.x,gsc.y,gsc.z,gsc.w};
  float ov_[4]={gof.x,gof.y,gof.z,gof.w};
  #pragma unroll
  for(int j=0;j<8;j++){
    float x[4];
    float s=0.f, ss=0.f;
    #pragma unroll
    for(int c=0;c<4;c++){
      float t = fmaxf(acc[j][c]+bv[c], 0.f);
      x[c]=t; s+=t; ss+=t*t;
    }
    #pragma unroll
    for(int m=1;m<=16;m<<=1){ s+=__shfl_xor(s,m); ss+=__shfl_xor(ss,m); }
    float mu = s*(1.0f/HH);
    float var = ss*(1.0f/HH) - mu*mu;
    float rs = rsqrtf(var + LNEPS);
    int node=node0+tr*8+j;
    if(node<NN){
      float4 o;
      o.x = sv[0]*(x[0]-mu)*rs + ov_[0];
      o.y = sv[1]*(x[1]-mu)*rs + ov_[1];
      o.z = sv[2]*(x[2]-mu)*rs + ov_[2];
      o.w = sv[3]*(x[3]-mu)*rs + ov_[3];
      *(float4*)&hout[(size_t)node*HH + tc*4]=o;
    }
  }
}

// ---------------- graph mean + output head ----------------
__global__ void k_mean(const float* __restrict__ h, float* __restrict__ g){
  int col=threadIdx.x; // 128 threads
  float s=0.f;
  for(int n=blockIdx.x; n<NN; n+=gridDim.x) s += h[(size_t)n*HH + col];
  atomicAdd(&g[col], s);
}

__global__ void k_out(const float* __restrict__ g, const float* __restrict__ Wout,
                      const float* __restrict__ bout, float* __restrict__ out){
  int o=threadIdx.x;
  if(o<OO){
    float acc=bout[o];
    for(int k=0;k<HH;k++) acc = fmaf(g[k]*(1.0f/NN), Wout[k*OO+o], acc);
    out[o]=acc;
  }
}

extern "C" void kernel_launch(void* const* d_in, const int* in_sizes, int n_in,
                              void* d_out, int out_size, void* d_ws, size_t ws_size,
                              hipStream_t stream){
  const float* nodes = (const float*)d_in[0];
  const int*   src   = (const int*)d_in[1];
  const int*   dst   = (const int*)d_in[2];
  const float* W_in1 = (const float*)d_in[3];
  const float* b_in1 = (const float*)d_in[4];
  const float* W_in2 = (const float*)d_in[5];
  const float* b_in2 = (const float*)d_in[6];
  const float* W_self  = (const float*)d_in[7];
  const float* W_neigh = (const float*)d_in[8];
  const float* b_sage  = (const float*)d_in[9];
  const float* ln_g    = (const float*)d_in[10];
  const float* ln_b    = (const float*)d_in[11];
  const float* W_out   = (const float*)d_in[12];
  const float* b_out   = (const float*)d_in[13];

  char* w=(char*)d_ws;
  float* h    = (float*)w; w += (size_t)NN*HH*4;   // 51.2 MB
  float* agg  = (float*)w; w += (size_t)NN*HH*4;   // 51.2 MB (also MLP intermediate)
  int* deg    = (int*)w;   w += (size_t)NN*4;
  int* rowoff = (int*)w;   w += (size_t)(NN+8)*4;
  int* cursor = (int*)w;   w += (size_t)NN*4;
  float* invd = (float*)w; w += (size_t)NN*4;
  int* csr    = (int*)w;   w += (size_t)NE*4;      // 6.4 MB
  int* bsum   = (int*)w;   w += 256*4;
  int* bexc   = (int*)w;   w += 256*4;
  float* gsum = (float*)w; w += 128*4;

  hipMemsetAsync(deg, 0, (size_t)NN*4, stream);
  hipMemsetAsync(cursor, 0, (size_t)NN*4, stream);
  hipMemsetAsync(gsum, 0, 128*4, stream);

  k_deg<<<(NE+255)/256,256,0,stream>>>(dst,deg);
  k_invdeg<<<(NN+255)/256,256,0,stream>>>(deg,invd);
  int nb=(NN+511)/512;
  k_scan1<<<nb,512,0,stream>>>(deg,rowoff,bsum);
  k_scan2<<<1,256,0,stream>>>(bsum,bexc,nb);
  k_scan3<<<nb,512,0,stream>>>(rowoff,bexc);
  k_scatter<<<(NE+255)/256,256,0,stream>>>(src,dst,rowoff,cursor,csr);

  k_gemm<FF,1><<<(NN+63)/64,256,0,stream>>>(nodes,W_in1,b_in1,agg);
  k_gemm<HH,0><<<(NN+63)/64,256,0,stream>>>(agg,W_in2,b_in2,h);

  for(int l=0;l<NL;l++){
    k_agg<<<(NN+3)/4,256,0,stream>>>(h,csr,rowoff,invd,agg);
    k_sage<<<(NN+63)/64,256,0,stream>>>(h,agg,
        W_self+(size_t)l*HH*HH, W_neigh+(size_t)l*HH*HH,
        b_sage+(size_t)l*HH, ln_g+(size_t)l*HH, ln_b+(size_t)l*HH, h);
  }
  k_mean<<<256,128,0,stream>>>(h,gsum);
  k_out<<<1,64,0,stream>>>(gsum,W_out,b_out,(float*)d_out);
}

// Round 2
// 936.796 us; speedup vs baseline: 1.2489x; 1.2489x over previous
//
#include <hip/hip_runtime.h>
#include <hip/hip_bf16.h>

#define NN 100000
#define NE 1600000
#define FF 64
#define HH 128
#define OO 10
#define NL 3
#define LNEPS 1e-5f

__device__ __forceinline__ unsigned short f2b(float f){
  unsigned u = __float_as_uint(f);
  unsigned r = (u + 0x7FFFu + ((u>>16)&1u)) >> 16;
  return (unsigned short)r;
}

// ---------------- CSR build ----------------
__global__ void k_deg(const int* __restrict__ dst, int* __restrict__ deg){
  int e = blockIdx.x*256 + threadIdx.x;
  if(e<NE) atomicAdd(&deg[dst[e]], 1);
}

__global__ void k_invdeg(const int* __restrict__ deg, float* __restrict__ invd){
  int i = blockIdx.x*256 + threadIdx.x;
  if(i<NN) invd[i] = 1.0f / fmaxf((float)deg[i], 1.0f);
}

__global__ void k_scan1(const int* __restrict__ deg, int* __restrict__ exc, int* __restrict__ bsum){
  __shared__ int s[512];
  int i = blockIdx.x*512 + threadIdx.x;
  int v = (i<NN)? deg[i] : 0;
  s[threadIdx.x] = v;
  __syncthreads();
  for(int off=1; off<512; off<<=1){
    int t = (threadIdx.x>= (unsigned)off)? s[threadIdx.x-off] : 0;
    __syncthreads();
    s[threadIdx.x] += t;
    __syncthreads();
  }
  if(i<NN) exc[i] = s[threadIdx.x] - v;
  if(threadIdx.x==511) bsum[blockIdx.x] = s[511];
}

__global__ void k_scan2(const int* __restrict__ bsum, int* __restrict__ bexc, int nb){
  __shared__ int s[256];
  int t = threadIdx.x;
  int v = (t<nb)? bsum[t] : 0;
  s[t]=v; __syncthreads();
  for(int off=1; off<256; off<<=1){
    int x = (t>=off)? s[t-off]:0;
    __syncthreads();
    s[t]+=x;
    __syncthreads();
  }
  if(t<nb) bexc[t] = s[t]-v;
}

__global__ void k_scan3(int* __restrict__ rowoff, const int* __restrict__ bexc){
  int i = blockIdx.x*512+threadIdx.x;
  if(i<NN) rowoff[i] += bexc[blockIdx.x];
  if(i==0) rowoff[NN] = NE;
}

__global__ void k_scatter(const int* __restrict__ src, const int* __restrict__ dst,
                          const int* __restrict__ rowoff, int* __restrict__ cursor,
                          int* __restrict__ csr){
  int e = blockIdx.x*256+threadIdx.x;
  if(e<NE){
    int d = dst[e];
    int p = atomicAdd(&cursor[d],1);
    csr[rowoff[d]+p] = src[e];
  }
}

// ---------------- mean aggregation: one wave per node, bf16 gather ----------------
__global__ __launch_bounds__(256) void k_agg(const unsigned* __restrict__ hb, const int* __restrict__ csr,
                                             const int* __restrict__ rowoff, const float* __restrict__ invd,
                                             float* __restrict__ agg){
  int wave = threadIdx.x>>6;
  int lane = threadIdx.x&63;
  int n = blockIdx.x*4 + wave;
  if(n>=NN) return;
  int beg=rowoff[n], end=rowoff[n+1];
  float ax=0.f, ay=0.f;
  int j=beg;
  for(; j+4<=end; j+=4){
    int s0=csr[j], s1=csr[j+1], s2=csr[j+2], s3=csr[j+3];
    unsigned u0 = hb[(size_t)s0*64 + lane];
    unsigned u1 = hb[(size_t)s1*64 + lane];
    unsigned u2 = hb[(size_t)s2*64 + lane];
    unsigned u3 = hb[(size_t)s3*64 + lane];
    ax += __uint_as_float(u0<<16) + __uint_as_float(u1<<16)
        + __uint_as_float(u2<<16) + __uint_as_float(u3<<16);
    ay += __uint_as_float(u0&0xFFFF0000u) + __uint_as_float(u1&0xFFFF0000u)
        + __uint_as_float(u2&0xFFFF0000u) + __uint_as_float(u3&0xFFFF0000u);
  }
  for(; j<end; j++){
    int s0=csr[j];
    unsigned u0 = hb[(size_t)s0*64 + lane];
    ax += __uint_as_float(u0<<16);
    ay += __uint_as_float(u0&0xFFFF0000u);
  }
  float sc = invd[n];
  ((float2*)agg)[(size_t)n*64+lane] = make_float2(ax*sc, ay*sc);
}

// ---------------- generic MLP GEMM: C = act(A[N,K] @ W[K,128] + b) ----------------
template<int K, int ACT, int WB>
__global__ __launch_bounds__(256) void k_gemm(const float* __restrict__ A, const float* __restrict__ W,
                                              const float* __restrict__ bias, float* __restrict__ C,
                                              unsigned* __restrict__ hb){
  __shared__ float As[32][68];
  __shared__ float Ws[32][128];
  int tid=threadIdx.x;
  int tc=tid&31, tr=tid>>5;
  int node0=blockIdx.x*64;
  float acc[8][4]={};
  for(int kc=0;kc<K;kc+=32){
    __syncthreads();
    #pragma unroll
    for(int q=0;q<2;q++){
      int idx=tid+256*q;
      int nl=idx>>3, kq=idx&7;
      int node=node0+nl;
      float4 v = make_float4(0.f,0.f,0.f,0.f);
      if(node<NN) v = *(const float4*)&A[(size_t)node*K + kc + kq*4];
      As[kq*4+0][nl]=v.x; As[kq*4+1][nl]=v.y; As[kq*4+2][nl]=v.z; As[kq*4+3][nl]=v.w;
    }
    #pragma unroll
    for(int q=0;q<4;q++){
      int idx=tid+256*q;
      int kl=idx>>5, cq=idx&31;
      *(float4*)&Ws[kl][cq*4] = *(const float4*)&W[(size_t)(kc+kl)*HH + cq*4];
    }
    __syncthreads();
    #pragma unroll
    for(int k=0;k<32;k++){
      float4 w=*(float4*)&Ws[k][tc*4];
      float4 a0=*(float4*)&As[k][tr*8];
      float4 a1=*(float4*)&As[k][tr*8+4];
      float av[8]={a0.x,a0.y,a0.z,a0.w,a1.x,a1.y,a1.z,a1.w};
      float wv[4]={w.x,w.y,w.z,w.w};
      #pragma unroll
      for(int j=0;j<8;j++)
        #pragma unroll
        for(int c=0;c<4;c++) acc[j][c] = fmaf(av[j], wv[c], acc[j][c]);
    }
  }
  float4 bb=*(const float4*)&bias[tc*4];
  float bv[4]={bb.x,bb.y,bb.z,bb.w};
  #pragma unroll
  for(int j=0;j<8;j++){
    int node=node0+tr*8+j;
    if(node<NN){
      float ov[4];
      #pragma unroll
      for(int c=0;c<4;c++){ float x=acc[j][c]+bv[c]; if(ACT) x=fmaxf(x,0.f); ov[c]=x; }
      float4 o; o.x=ov[0]; o.y=ov[1]; o.z=ov[2]; o.w=ov[3];
      *(float4*)&C[(size_t)node*HH + tc*4]=o;
      if(WB){
        uint2 p;
        p.x = (unsigned)f2b(ov[0]) | ((unsigned)f2b(ov[1])<<16);
        p.y = (unsigned)f2b(ov[2]) | ((unsigned)f2b(ov[3])<<16);
        *(uint2*)&hb[(size_t)node*64 + tc*2] = p;
      }
    }
  }
}

// ---------------- fused SAGE layer: h = LN(relu(h@Ws + agg@Wn + b)) ----------------
template<int WB>
__global__ __launch_bounds__(256) void k_sage(const float* __restrict__ h, const float* __restrict__ ag,
                                              const float* __restrict__ Wself, const float* __restrict__ Wneigh,
                                              const float* __restrict__ bias, const float* __restrict__ lng,
                                              const float* __restrict__ lnb, float* __restrict__ hout,
                                              unsigned* __restrict__ hb){
  __shared__ float Ah[32][68], Ag[32][68];
  __shared__ float Ws[32][128], Wn[32][128];
  int tid=threadIdx.x, tc=tid&31, tr=tid>>5;
  int node0=blockIdx.x*64;
  float acc[8][4]={};
  for(int kc=0;kc<HH;kc+=32){
    __syncthreads();
    #pragma unroll
    for(int q=0;q<2;q++){
      int idx=tid+256*q;
      int nl=idx>>3, kq=idx&7;
      int node=node0+nl;
      float4 v=make_float4(0.f,0.f,0.f,0.f), u=make_float4(0.f,0.f,0.f,0.f);
      if(node<NN){
        v=*(const float4*)&h[(size_t)node*HH+kc+kq*4];
        u=*(const float4*)&ag[(size_t)node*HH+kc+kq*4];
      }
      Ah[kq*4+0][nl]=v.x; Ah[kq*4+1][nl]=v.y; Ah[kq*4+2][nl]=v.z; Ah[kq*4+3][nl]=v.w;
      Ag[kq*4+0][nl]=u.x; Ag[kq*4+1][nl]=u.y; Ag[kq*4+2][nl]=u.z; Ag[kq*4+3][nl]=u.w;
    }
    #pragma unroll
    for(int q=0;q<4;q++){
      int idx=tid+256*q;
      int kl=idx>>5, cq=idx&31;
      *(float4*)&Ws[kl][cq*4]=*(const float4*)&Wself[(size_t)(kc+kl)*HH+cq*4];
      *(float4*)&Wn[kl][cq*4]=*(const float4*)&Wneigh[(size_t)(kc+kl)*HH+cq*4];
    }
    __syncthreads();
    #pragma unroll
    for(int k=0;k<32;k++){
      float4 w1=*(float4*)&Ws[k][tc*4];
      float4 w2=*(float4*)&Wn[k][tc*4];
      float4 a0=*(float4*)&Ah[k][tr*8];
      float4 a1=*(float4*)&Ah[k][tr*8+4];
      float4 g0=*(float4*)&Ag[k][tr*8];
      float4 g1=*(float4*)&Ag[k][tr*8+4];
      float av[8]={a0.x,a0.y,a0.z,a0.w,a1.x,a1.y,a1.z,a1.w};
      float gv[8]={g0.x,g0.y,g0.z,g0.w,g1.x,g1.y,g1.z,g1.w};
      float w1v[4]={w1.x,w1.y,w1.z,w1.w};
      float w2v[4]={w2.x,w2.y,w2.z,w2.w};
      #pragma unroll
      for(int j=0;j<8;j++)
        #pragma unroll
        for(int c=0;c<4;c++)
          acc[j][c] = fmaf(gv[j], w2v[c], fmaf(av[j], w1v[c], acc[j][c]));
    }
  }
  float4 bb=*(const float4*)&bias[tc*4];
  float4 gsc=*(const float4*)&lng[tc*4];
  float4 gof=*(const float4*)&lnb[tc*4];
  float bv[4]={bb.x,bb.y,bb.z,bb.w};
  float sv[4]={gsc.x,gsc.y,gsc.z,gsc.w};
  float ov_[4]={gof.x,gof.y,gof.z,gof.w};
  #pragma unroll
  for(int j=0;j<8;j++){
    float x[4];
    float s=0.f, ss=0.f;
    #pragma unroll
    for(int c=0;c<4;c++){
      float t = fmaxf(acc[j][c]+bv[c], 0.f);
      x[c]=t; s+=t; ss+=t*t;
    }
    #pragma unroll
    for(int m=1;m<=16;m<<=1){ s+=__shfl_xor(s,m); ss+=__shfl_xor(ss,m); }
    float mu = s*(1.0f/HH);
    float var = ss*(1.0f/HH) - mu*mu;
    float rs = rsqrtf(var + LNEPS);
    int node=node0+tr*8+j;
    if(node<NN){
      float4 o;
      o.x = sv[0]*(x[0]-mu)*rs + ov_[0];
      o.y = sv[1]*(x[1]-mu)*rs + ov_[1];
      o.z = sv[2]*(x[2]-mu)*rs + ov_[2];
      o.w = sv[3]*(x[3]-mu)*rs + ov_[3];
      *(float4*)&hout[(size_t)node*HH + tc*4]=o;
      if(WB){
        uint2 p;
        p.x = (unsigned)f2b(o.x) | ((unsigned)f2b(o.y)<<16);
        p.y = (unsigned)f2b(o.z) | ((unsigned)f2b(o.w)<<16);
        *(uint2*)&hb[(size_t)node*64 + tc*2] = p;
      }
    }
  }
}

// ---------------- graph mean + output head ----------------
__global__ void k_mean(const float* __restrict__ h, float* __restrict__ g){
  int col=threadIdx.x; // 128 threads
  float s=0.f;
  for(int n=blockIdx.x; n<NN; n+=gridDim.x) s += h[(size_t)n*HH + col];
  atomicAdd(&g[col], s);
}

__global__ void k_out(const float* __restrict__ g, const float* __restrict__ Wout,
                      const float* __restrict__ bout, float* __restrict__ out){
  int o=threadIdx.x;
  if(o<OO){
    float acc=bout[o];
    for(int k=0;k<HH;k++) acc = fmaf(g[k]*(1.0f/NN), Wout[k*OO+o], acc);
    out[o]=acc;
  }
}

extern "C" void kernel_launch(void* const* d_in, const int* in_sizes, int n_in,
                              void* d_out, int out_size, void* d_ws, size_t ws_size,
                              hipStream_t stream){
  const float* nodes = (const float*)d_in[0];
  const int*   src   = (const int*)d_in[1];
  const int*   dst   = (const int*)d_in[2];
  const float* W_in1 = (const float*)d_in[3];
  const float* b_in1 = (const float*)d_in[4];
  const float* W_in2 = (const float*)d_in[5];
  const float* b_in2 = (const float*)d_in[6];
  const float* W_self  = (const float*)d_in[7];
  const float* W_neigh = (const float*)d_in[8];
  const float* b_sage  = (const float*)d_in[9];
  const float* ln_g    = (const float*)d_in[10];
  const float* ln_b    = (const float*)d_in[11];
  const float* W_out   = (const float*)d_in[12];
  const float* b_out   = (const float*)d_in[13];

  char* w=(char*)d_ws;
  float* h    = (float*)w; w += (size_t)NN*HH*4;   // 51.2 MB
  float* agg  = (float*)w; w += (size_t)NN*HH*4;   // 51.2 MB (also MLP intermediate)
  unsigned* hb= (unsigned*)w; w += (size_t)NN*64*4; // 25.6 MB bf16 shadow of h
  int* deg    = (int*)w;   w += (size_t)NN*4;
  int* rowoff = (int*)w;   w += (size_t)(NN+8)*4;
  int* cursor = (int*)w;   w += (size_t)NN*4;
  float* invd = (float*)w; w += (size_t)NN*4;
  int* csr    = (int*)w;   w += (size_t)NE*4;      // 6.4 MB
  int* bsum   = (int*)w;   w += 256*4;
  int* bexc   = (int*)w;   w += 256*4;
  float* gsum = (float*)w; w += 128*4;

  hipMemsetAsync(deg, 0, (size_t)NN*4, stream);
  hipMemsetAsync(cursor, 0, (size_t)NN*4, stream);
  hipMemsetAsync(gsum, 0, 128*4, stream);

  k_deg<<<(NE+255)/256,256,0,stream>>>(dst,deg);
  k_invdeg<<<(NN+255)/256,256,0,stream>>>(deg,invd);
  int nb=(NN+511)/512;
  k_scan1<<<nb,512,0,stream>>>(deg,rowoff,bsum);
  k_scan2<<<1,256,0,stream>>>(bsum,bexc,nb);
  k_scan3<<<nb,512,0,stream>>>(rowoff,bexc);
  k_scatter<<<(NE+255)/256,256,0,stream>>>(src,dst,rowoff,cursor,csr);

  k_gemm<FF,1,0><<<(NN+63)/64,256,0,stream>>>(nodes,W_in1,b_in1,agg,nullptr);
  k_gemm<HH,0,1><<<(NN+63)/64,256,0,stream>>>(agg,W_in2,b_in2,h,hb);

  for(int l=0;l<NL;l++){
    k_agg<<<(NN+3)/4,256,0,stream>>>(hb,csr,rowoff,invd,agg);
    if(l<NL-1)
      k_sage<1><<<(NN+63)/64,256,0,stream>>>(h,agg,
          W_self+(size_t)l*HH*HH, W_neigh+(size_t)l*HH*HH,
          b_sage+(size_t)l*HH, ln_g+(size_t)l*HH, ln_b+(size_t)l*HH, h, hb);
    else
      k_sage<0><<<(NN+63)/64,256,0,stream>>>(h,agg,
          W_self+(size_t)l*HH*HH, W_neigh+(size_t)l*HH*HH,
          b_sage+(size_t)l*HH, ln_g+(size_t)l*HH, ln_b+(size_t)l*HH, h, nullptr);
  }
  k_mean<<<256,128,0,stream>>>(h,gsum);
  k_out<<<1,64,0,stream>>>(gsum,W_out,b_out,(float*)d_out);
}

// Round 3
// 607.364 us; speedup vs baseline: 1.9263x; 1.5424x over previous
//
#include <hip/hip_runtime.h>
#include <hip/hip_bf16.h>

#define NN 100000
#define NE 1600000
#define FF 64
#define HH 128
#define OO 10
#define NL 3
#define LNEPS 1e-5f

typedef short s8v __attribute__((ext_vector_type(8)));   // 8 bf16 = 4 VGPR
typedef float f32x4 __attribute__((ext_vector_type(4)));

__device__ __forceinline__ unsigned short f2b(float f){
  unsigned u = __float_as_uint(f);
  unsigned r = (u + 0x7FFFu + ((u>>16)&1u)) >> 16;
  return (unsigned short)r;
}
__device__ __forceinline__ float b2f(unsigned short b){
  return __uint_as_float(((unsigned)b)<<16);
}

// ---------------- CSR build ----------------
__global__ void k_deg(const int* __restrict__ dst, int* __restrict__ deg){
  int e = blockIdx.x*256 + threadIdx.x;
  if(e<NE) atomicAdd(&deg[dst[e]], 1);
}

__global__ void k_invdeg(const int* __restrict__ deg, float* __restrict__ invd){
  int i = blockIdx.x*256 + threadIdx.x;
  if(i<NN) invd[i] = 1.0f / fmaxf((float)deg[i], 1.0f);
}

__global__ void k_scan1(const int* __restrict__ deg, int* __restrict__ exc, int* __restrict__ bsum){
  __shared__ int s[512];
  int i = blockIdx.x*512 + threadIdx.x;
  int v = (i<NN)? deg[i] : 0;
  s[threadIdx.x] = v;
  __syncthreads();
  for(int off=1; off<512; off<<=1){
    int t = (threadIdx.x>= (unsigned)off)? s[threadIdx.x-off] : 0;
    __syncthreads();
    s[threadIdx.x] += t;
    __syncthreads();
  }
  if(i<NN) exc[i] = s[threadIdx.x] - v;
  if(threadIdx.x==511) bsum[blockIdx.x] = s[511];
}

__global__ void k_scan2(const int* __restrict__ bsum, int* __restrict__ bexc, int nb){
  __shared__ int s[256];
  int t = threadIdx.x;
  int v = (t<nb)? bsum[t] : 0;
  s[t]=v; __syncthreads();
  for(int off=1; off<256; off<<=1){
    int x = (t>=off)? s[t-off]:0;
    __syncthreads();
    s[t]+=x;
    __syncthreads();
  }
  if(t<nb) bexc[t] = s[t]-v;
}

__global__ void k_scan3(int* __restrict__ rowoff, const int* __restrict__ bexc){
  int i = blockIdx.x*512+threadIdx.x;
  if(i<NN) rowoff[i] += bexc[blockIdx.x];
  if(i==0) rowoff[NN] = NE;
}

__global__ void k_scatter(const int* __restrict__ src, const int* __restrict__ dst,
                          const int* __restrict__ rowoff, int* __restrict__ cursor,
                          int* __restrict__ csr){
  int e = blockIdx.x*256+threadIdx.x;
  if(e<NE){
    int d = dst[e];
    int p = atomicAdd(&cursor[d],1);
    csr[rowoff[d]+p] = src[e];
  }
}

// ---------------- input conversion & weight repack ----------------
__global__ void k_cvtin(const float* __restrict__ x, unsigned* __restrict__ xb, int n4){
  int i = blockIdx.x*256+threadIdx.x;
  if(i<n4){
    float4 v = *(const float4*)&x[i*4];
    uint2 p;
    p.x = (unsigned)f2b(v.x) | ((unsigned)f2b(v.y)<<16);
    p.y = (unsigned)f2b(v.z) | ((unsigned)f2b(v.w)<<16);
    *(uint2*)&xb[i*2] = p;
  }
}

// frag-ready layout: dst[((kcb*8 + nt)*64 + l)*8 + j] = bf16(W[(kcb*32 + 8*(l>>4) + j)*128 + nt*16 + (l&15)])
// offsets in wf (ushort): W1f@0 (8192), W2f@8192 (16384), Wsf[l]@24576+l*16384, Wnf[l]@73728+l*16384
__global__ void k_repack(const float* __restrict__ W1, const float* __restrict__ W2,
                         const float* __restrict__ Ws, const float* __restrict__ Wn,
                         unsigned short* __restrict__ wf){
  int t = blockIdx.x*256+threadIdx.x;
  if(t >= 122880) return;
  const float* src; int rem;
  if(t < 8192){ src = W1; rem = t; }
  else {
    int u = t - 8192;
    int m = u >> 14; rem = u & 16383;
    if(m==0) src = W2;
    else if(m<=3) src = Ws + (size_t)(m-1)*HH*HH;
    else src = Wn + (size_t)(m-4)*HH*HH;
  }
  int j = rem&7, l=(rem>>3)&63, nt=(rem>>9)&7, kcb=rem>>12;
  int k = kcb*32 + 8*(l>>4) + j;
  int n = nt*16 + (l&15);
  wf[t] = f2b(src[(size_t)k*HH + n]);
}

// ---------------- mean aggregation: one wave per node, bf16 in/out ----------------
__global__ __launch_bounds__(256) void k_agg(const unsigned* __restrict__ hb, const int* __restrict__ csr,
                                             const int* __restrict__ rowoff, const float* __restrict__ invd,
                                             unsigned* __restrict__ aggb){
  int wave = threadIdx.x>>6;
  int lane = threadIdx.x&63;
  int n = blockIdx.x*4 + wave;
  if(n>=NN) return;
  int beg=rowoff[n], end=rowoff[n+1];
  float ax=0.f, ay=0.f;
  int j=beg;
  for(; j+4<=end; j+=4){
    int s0=csr[j], s1=csr[j+1], s2=csr[j+2], s3=csr[j+3];
    unsigned u0 = hb[(size_t)s0*64 + lane];
    unsigned u1 = hb[(size_t)s1*64 + lane];
    unsigned u2 = hb[(size_t)s2*64 + lane];
    unsigned u3 = hb[(size_t)s3*64 + lane];
    ax += __uint_as_float(u0<<16) + __uint_as_float(u1<<16)
        + __uint_as_float(u2<<16) + __uint_as_float(u3<<16);
    ay += __uint_as_float(u0&0xFFFF0000u) + __uint_as_float(u1&0xFFFF0000u)
        + __uint_as_float(u2&0xFFFF0000u) + __uint_as_float(u3&0xFFFF0000u);
  }
  for(; j<end; j++){
    int s0=csr[j];
    unsigned u0 = hb[(size_t)s0*64 + lane];
    ax += __uint_as_float(u0<<16);
    ay += __uint_as_float(u0&0xFFFF0000u);
  }
  float sc = invd[n];
  aggb[(size_t)n*64 + lane] = (unsigned)f2b(ax*sc) | ((unsigned)f2b(ay*sc)<<16);
}

// ---------------- MFMA GEMM: out_bf16 = [LN](act(A@W [+ A2@W2] + b)) ----------------
// block = 64 rows x 128 cols, 4 waves; wave w owns rows w*16..w*16+15.
template<int K, int DUAL, int RELU, int LN>
__global__ __launch_bounds__(256) void k_mfma(
    const unsigned short* __restrict__ A, const unsigned short* __restrict__ A2,
    const unsigned short* __restrict__ Wf, const unsigned short* __restrict__ Wf2,
    const float* __restrict__ bias, const float* __restrict__ lng, const float* __restrict__ lnb,
    unsigned short* __restrict__ out)
{
  constexpr int KC = K/32;
  __shared__ unsigned short Wl[KC*8*64*8];
  __shared__ unsigned short Wl2[DUAL ? KC*8*64*8 : 8];
  int tid = threadIdx.x;
  {
    const int tot = KC*8*64*8/8;  // uint4 count
    for(int i=tid;i<tot;i+=256){
      ((uint4*)Wl)[i] = ((const uint4*)Wf)[i];
      if(DUAL) ((uint4*)Wl2)[i] = ((const uint4*)Wf2)[i];
    }
  }
  __syncthreads();
  int l = tid&63, wv = tid>>6;
  int grp = l>>4, lc = l&15;
  int node0 = blockIdx.x*64 + wv*16;
  int arow = node0 + lc; if(arow > NN-1) arow = NN-1;
  f32x4 acc[8] = {};
  const s8v* Wv  = (const s8v*)Wl;
  const s8v* Wv2 = (const s8v*)Wl2;
  #pragma unroll
  for(int kcb=0;kcb<KC;kcb++){
    s8v a = *(const s8v*)&A[(size_t)arow*K + kcb*32 + 8*grp];
    s8v a2;
    if(DUAL) a2 = *(const s8v*)&A2[(size_t)arow*K + kcb*32 + 8*grp];
    #pragma unroll
    for(int nt=0;nt<8;nt++){
      acc[nt] = __builtin_amdgcn_mfma_f32_16x16x32_bf16(a, Wv[(kcb*8+nt)*64 + l], acc[nt], 0,0,0);
      if(DUAL)
        acc[nt] = __builtin_amdgcn_mfma_f32_16x16x32_bf16(a2, Wv2[(kcb*8+nt)*64 + l], acc[nt], 0,0,0);
    }
  }
  // epilogue: C/D map col=lane&15, row=(lane>>4)*4+reg
  float bc[8], gc[8], oc[8];
  #pragma unroll
  for(int nt=0;nt<8;nt++){
    bc[nt] = bias[nt*16+lc];
    if(LN){ gc[nt]=lng[nt*16+lc]; oc[nt]=lnb[nt*16+lc]; }
  }
  #pragma unroll
  for(int r=0;r<4;r++){
    float x[8]; float s=0.f, ss=0.f;
    #pragma unroll
    for(int nt=0;nt<8;nt++){
      float v = acc[nt][r] + bc[nt];
      if(RELU) v = fmaxf(v, 0.f);
      x[nt]=v; s+=v; ss+=v*v;
    }
    if(LN){
      #pragma unroll
      for(int m=1;m<=8;m<<=1){ s+=__shfl_xor(s,m); ss+=__shfl_xor(ss,m); }
      float mu = s*(1.0f/HH);
      float var = ss*(1.0f/HH) - mu*mu;
      float rs = rsqrtf(var + LNEPS);
      #pragma unroll
      for(int nt=0;nt<8;nt++) x[nt] = gc[nt]*(x[nt]-mu)*rs + oc[nt];
    }
    int node = node0 + grp*4 + r;
    if(node<NN){
      #pragma unroll
      for(int nt=0;nt<8;nt++) out[(size_t)node*HH + nt*16 + lc] = f2b(x[nt]);
    }
  }
}

// ---------------- graph mean + output head ----------------
__global__ void k_mean(const unsigned short* __restrict__ hb, float* __restrict__ g){
  int col=threadIdx.x; // 128 threads
  float s=0.f;
  for(int n=blockIdx.x; n<NN; n+=gridDim.x) s += b2f(hb[(size_t)n*HH + col]);
  atomicAdd(&g[col], s);
}

__global__ void k_out(const float* __restrict__ g, const float* __restrict__ Wout,
                      const float* __restrict__ bout, float* __restrict__ out){
  int o=threadIdx.x;
  if(o<OO){
    float acc=bout[o];
    for(int k=0;k<HH;k++) acc = fmaf(g[k]*(1.0f/NN), Wout[k*OO+o], acc);
    out[o]=acc;
  }
}

extern "C" void kernel_launch(void* const* d_in, const int* in_sizes, int n_in,
                              void* d_out, int out_size, void* d_ws, size_t ws_size,
                              hipStream_t stream){
  const float* nodes = (const float*)d_in[0];
  const int*   src   = (const int*)d_in[1];
  const int*   dst   = (const int*)d_in[2];
  const float* W_in1 = (const float*)d_in[3];
  const float* b_in1 = (const float*)d_in[4];
  const float* W_in2 = (const float*)d_in[5];
  const float* b_in2 = (const float*)d_in[6];
  const float* W_self  = (const float*)d_in[7];
  const float* W_neigh = (const float*)d_in[8];
  const float* b_sage  = (const float*)d_in[9];
  const float* ln_g    = (const float*)d_in[10];
  const float* ln_b    = (const float*)d_in[11];
  const float* W_out   = (const float*)d_in[12];
  const float* b_out   = (const float*)d_in[13];

  char* w=(char*)d_ws;
  unsigned short* hb   = (unsigned short*)w; w += (size_t)NN*HH*2;   // 25.6 MB
  unsigned short* aggb = (unsigned short*)w; w += (size_t)NN*HH*2;   // 25.6 MB (also MLP intermediate t)
  unsigned short* xb   = (unsigned short*)w; w += (size_t)NN*FF*2;   // 12.8 MB bf16 nodes
  unsigned short* wf   = (unsigned short*)w; w += (size_t)122880*2;  // repacked weights
  int* deg    = (int*)w;   w += (size_t)NN*4;
  int* rowoff = (int*)w;   w += (size_t)(NN+8)*4;
  int* cursor = (int*)w;   w += (size_t)NN*4;
  float* invd = (float*)w; w += (size_t)NN*4;
  int* csr    = (int*)w;   w += (size_t)NE*4;      // 6.4 MB
  int* bsum   = (int*)w;   w += 256*4;
  int* bexc   = (int*)w;   w += 256*4;
  float* gsum = (float*)w; w += 128*4;

  hipMemsetAsync(deg, 0, (size_t)NN*4, stream);
  hipMemsetAsync(cursor, 0, (size_t)NN*4, stream);
  hipMemsetAsync(gsum, 0, 128*4, stream);

  k_deg<<<(NE+255)/256,256,0,stream>>>(dst,deg);
  k_invdeg<<<(NN+255)/256,256,0,stream>>>(deg,invd);
  int nb=(NN+511)/512;
  k_scan1<<<nb,512,0,stream>>>(deg,rowoff,bsum);
  k_scan2<<<1,256,0,stream>>>(bsum,bexc,nb);
  k_scan3<<<nb,512,0,stream>>>(rowoff,bexc);
  k_scatter<<<(NE+255)/256,256,0,stream>>>(src,dst,rowoff,cursor,csr);

  k_cvtin<<<((NN*FF/4)+255)/256,256,0,stream>>>(nodes,(unsigned*)xb, NN*FF/4);
  k_repack<<<(122880+255)/256,256,0,stream>>>(W_in1,W_in2,W_self,W_neigh,wf);

  const int GB = (NN+63)/64;
  // input MLP: t = relu(x@W1+b1)  (bf16 out, reuse aggb as t)
  k_mfma<FF,0,1,0><<<GB,256,0,stream>>>(xb,nullptr, wf, nullptr, b_in1,nullptr,nullptr, aggb);
  // h = t@W2 + b2
  k_mfma<HH,0,0,0><<<GB,256,0,stream>>>(aggb,nullptr, wf+8192, nullptr, b_in2,nullptr,nullptr, hb);

  for(int l=0;l<NL;l++){
    k_agg<<<(NN+3)/4,256,0,stream>>>((const unsigned*)hb,csr,rowoff,invd,(unsigned*)aggb);
    k_mfma<HH,1,1,1><<<GB,256,0,stream>>>(hb, aggb,
        wf+24576+(size_t)l*16384, wf+73728+(size_t)l*16384,
        b_sage+(size_t)l*HH, ln_g+(size_t)l*HH, ln_b+(size_t)l*HH, hb);
  }
  k_mean<<<256,128,0,stream>>>(hb,gsum);
  k_out<<<1,64,0,stream>>>(gsum,W_out,b_out,(float*)d_out);
}